// Round 2
// baseline (604.719 us; speedup 1.0000x reference)
//
#include <hip/hip_runtime.h>
#include <hip/hip_bf16.h>
#include <math.h>

#define B_ 16
#define T_ 12
#define N_ 325
#define DIMS_ 40
#define DAYS_ 288

// ---------------- mask dtype detection + canonicalization ----------------
// geo_mask is bool in the reference; harness may push it as uint8/int32/bf16/f32.
// Detect from byte patterns, convert to canonical uint8 (0/1).
// modes: 0=uint8, 1=int32, 2=bf16, 3=f32
__global__ void mask_detect(const unsigned char* __restrict__ raw, int* __restrict__ mode){
  __shared__ int f3F_m1, f3F_m3, fNZ_o;
  if (threadIdx.x == 0){ f3F_m1 = 0; f3F_m3 = 0; fNZ_o = 0; }
  __syncthreads();
  for (int i = threadIdx.x; i < 4096; i += 256){
    unsigned char v = raw[i];
    int m4 = i & 3;
    if (v == 0x3F && m4 == 1) atomicOr(&f3F_m1, 1);
    if (v == 0x3F && m4 == 3) atomicOr(&f3F_m3, 1);
    if (v != 0 && m4 != 0)    atomicOr(&fNZ_o, 1);
  }
  __syncthreads();
  if (threadIdx.x == 0){
    int m;
    if (f3F_m1) m = 2;        // bf16: 1.0 = 0x3F80, high byte at odd offsets (mod4 = 1 and 3)
    else if (f3F_m3) m = 3;   // f32: 1.0f = 0x3F800000, 0x3F only at mod4==3
    else if (fNZ_o) m = 0;    // uint8: 0/1 bytes at all offsets
    else m = 1;               // int32: nonzero only at mod4==0
    *mode = m;
  }
}

__global__ void mask_conv(const unsigned char* __restrict__ raw, const int* __restrict__ mode_p,
                          unsigned char* __restrict__ msk){
  int mode = *mode_p;
  int i = blockIdx.x * 256 + threadIdx.x;
  if (i >= N_ * N_) return;
  unsigned char r;
  if (mode == 0)      r = raw[i] != 0;
  else if (mode == 1) r = ((const int*)raw)[i] != 0;
  else if (mode == 2) { unsigned short u = ((const unsigned short*)raw)[i]; r = (u & 0x7FFF) != 0; }
  else                { float f = ((const float*)raw)[i]; r = (f != 0.f); }
  msk[i] = r;
}

// ---------------- dynamic graph construct ----------------
// A1[b,j,k] = sum_i te[b,i] * pk[i,j,k],  te = p1[ind[b] % DAYS]
__global__ void dg_a1(const float* __restrict__ p1, const float* __restrict__ pk,
                      const int* __restrict__ ind, float* __restrict__ A1){
  int b = blockIdx.x;
  __shared__ float te[DIMS_];
  int day = ind[b] % DAYS_; if (day < 0) day += DAYS_;
  for (int i = threadIdx.x; i < DIMS_; i += blockDim.x) te[i] = p1[day*DIMS_ + i];
  __syncthreads();
  for (int jk = threadIdx.x; jk < DIMS_*DIMS_; jk += blockDim.x){
    float acc = 0.f;
    for (int i = 0; i < DIMS_; ++i) acc += te[i] * pk[i*DIMS_*DIMS_ + jk];
    A1[b*DIMS_*DIMS_ + jk] = acc;
  }
}

// adp[b,n,c] = softmax_c( relu( sum_k p3[c,k] * (sum_j p2[n,j]*A1[b,j,k]) ) )
__global__ void dg_adp(const float* __restrict__ p2, const float* __restrict__ p3,
                       const float* __restrict__ A1, float* __restrict__ adp){
  int bid = blockIdx.x; int b = bid / N_; int n = bid % N_;
  __shared__ float p2r[DIMS_], t2[DIMS_], sbuf[N_], red[128];
  int tid = threadIdx.x;
  if (tid < DIMS_) p2r[tid] = p2[n*DIMS_ + tid];
  __syncthreads();
  if (tid < DIMS_){
    float acc = 0.f;
    const float* a1 = A1 + b*DIMS_*DIMS_;
    for (int j = 0; j < DIMS_; ++j) acc += p2r[j] * a1[j*DIMS_ + tid];
    t2[tid] = acc;
  }
  __syncthreads();
  float lm = -INFINITY;
  for (int c = tid; c < N_; c += 128){
    float acc = 0.f;
    for (int k = 0; k < DIMS_; ++k) acc += p3[c*DIMS_ + k] * t2[k];
    acc = fmaxf(acc, 0.f);
    sbuf[c] = acc; lm = fmaxf(lm, acc);
  }
  red[tid] = lm; __syncthreads();
  for (int off = 64; off; off >>= 1){ if (tid < off) red[tid] = fmaxf(red[tid], red[tid+off]); __syncthreads(); }
  float m = red[0]; __syncthreads();
  float ls = 0.f;
  for (int c = tid; c < N_; c += 128){ float e = __expf(sbuf[c] - m); sbuf[c] = e; ls += e; }
  red[tid] = ls; __syncthreads();
  for (int off = 64; off; off >>= 1){ if (tid < off) red[tid] += red[tid+off]; __syncthreads(); }
  float inv = 1.f / red[0];
  float* outp = adp + ((size_t)b*N_ + n) * N_;
  for (int c = tid; c < N_; c += 128) outp[c] = sbuf[c] * inv;
}

// ---------------- weight prep ----------------
// Wc[d,c] = sum_o W_r2[d,o]*W_gcn[o,c]; bc[d] = W_r2[d,:]@b_gcn + b_r2[d]
// Wall[j,d]: rows 0-15 Wtq, 16-31 Wtk, 32-47 Wtv, 48-79 Wgq, 80-111 Wgk, 112-143 Wgv
__global__ void prep_weights(const float* W_gcn, const float* b_gcn, const float* W_r2, const float* b_r2,
                             const float* Wtq, const float* Wtk, const float* Wtv,
                             const float* Wgq, const float* Wgk, const float* Wgv,
                             float* Wc, float* bc, float* Wall){
  if (blockIdx.x == 0){
    for (int idx = threadIdx.x; idx < 64*96; idx += blockDim.x){
      int d = idx / 96, c = idx % 96;
      float acc = 0.f;
      for (int o = 0; o < 32; ++o) acc += W_r2[d*32 + o] * W_gcn[o*96 + c];
      Wc[idx] = acc;
    }
    for (int d = threadIdx.x; d < 64; d += blockDim.x){
      float acc = b_r2[d];
      for (int o = 0; o < 32; ++o) acc += W_r2[d*32 + o] * b_gcn[o];
      bc[d] = acc;
    }
  } else {
    for (int idx = threadIdx.x; idx < 144*64; idx += blockDim.x){
      int j = idx >> 6, d = idx & 63;
      const float* src; int r;
      if      (j < 16) { src = Wtq; r = j; }
      else if (j < 32) { src = Wtk; r = j - 16; }
      else if (j < 48) { src = Wtv; r = j - 32; }
      else if (j < 80) { src = Wgq; r = j - 48; }
      else if (j < 112){ src = Wgk; r = j - 80; }
      else             { src = Wgv; r = j - 112; }
      Wall[idx] = src[r*64 + d];
    }
  }
}

// ---------------- h projection ----------------
// h[(b*N+n)*384 + c*12+t] = x[b,t,n,:] @ W_r1[c,:] + b_r1[c]
__global__ void hproj(const float* __restrict__ x, const float* __restrict__ W_r1,
                      const float* __restrict__ b_r1, float* __restrict__ h){
  int bid = blockIdx.x; int b = bid / N_, n = bid % N_;
  __shared__ float xs[T_*65], Ws[32*65];
  int tid = threadIdx.x;
  for (int idx = tid; idx < 32*64; idx += 384){ int c = idx >> 6, d = idx & 63; Ws[c*65 + d] = W_r1[idx]; }
  for (int idx = tid; idx < T_*64; idx += 384){
    int t = idx >> 6, d = idx & 63;
    xs[t*65 + d] = x[(((size_t)b*T_ + t)*N_ + n)*64 + d];
  }
  __syncthreads();
  int c = tid / T_, t = tid % T_;
  float acc = b_r1[c];
  for (int d = 0; d < 64; ++d) acc += xs[t*65 + d] * Ws[c*65 + d];
  h[((size_t)b*N_ + n)*384 + c*T_ + t] = acc;
}

// ---------------- GCN hop: out[b,w,ct] = sum_v adp[b,w,v] * in[b,v,ct] ----------------
__global__ void gcn_mm(const float* __restrict__ adp, const float* __restrict__ in,
                       float* __restrict__ out){
  int bid = blockIdx.x;
  int b = bid / 41, wt = bid % 41;
  int w0 = wt * 8;
  __shared__ float a_s[8*64];
  int tid = threadIdx.x;
  float acc[8] = {0,0,0,0,0,0,0,0};
  const float* inb = in + (size_t)b*N_*384 + tid;
  const float* adpb = adp + (size_t)b*N_*N_;
  for (int v0 = 0; v0 < N_; v0 += 64){
    int vn = N_ - v0; if (vn > 64) vn = 64;
    __syncthreads();
    for (int idx = tid; idx < 8*64; idx += 384){
      int wr = idx >> 6, v = idx & 63;
      int w = w0 + wr;
      a_s[idx] = (w < N_ && v < vn) ? adpb[(size_t)w*N_ + v0 + v] : 0.f;
    }
    __syncthreads();
    for (int v = 0; v < vn; ++v){
      float hv = inb[(size_t)(v0 + v)*384];
      #pragma unroll
      for (int w8 = 0; w8 < 8; ++w8) acc[w8] += a_s[w8*64 + v] * hv;
    }
  }
  for (int w8 = 0; w8 < 8; ++w8){
    int w = w0 + w8;
    if (w < N_) out[((size_t)b*N_ + w)*384 + tid] = acc[w8];
  }
}

// ---------------- fused gcn-mlp + reshape2 ----------------
// xg[b,t,n,d] = sum_c Wc[d,c]*cat[c, t] + bc[d],  cat = [h; x1; x2] rows of (b,n)
__global__ void xg_k(const float* __restrict__ h, const float* __restrict__ x1,
                     const float* __restrict__ x2, const float* __restrict__ Wc,
                     const float* __restrict__ bc, float* __restrict__ xg){
  int bid = blockIdx.x; int b = bid / N_, n = bid % N_;
  __shared__ float Wcs[64*97], cat_s[96*T_], bcs[64];
  int tid = threadIdx.x;
  for (int idx = tid; idx < 64*96; idx += 256){ int d = idx/96, c = idx%96; Wcs[d*97 + c] = Wc[idx]; }
  if (tid < 64) bcs[tid] = bc[tid];
  size_t base = ((size_t)b*N_ + n)*384;
  for (int idx = tid; idx < 384; idx += 256){
    cat_s[idx]       = h [base + idx];
    cat_s[384 + idx] = x1[base + idx];
    cat_s[768 + idx] = x2[base + idx];
  }
  __syncthreads();
  for (int o = tid; o < 768; o += 256){
    int t = o >> 6, d = o & 63;
    float acc = bcs[d];
    for (int c = 0; c < 96; ++c) acc += Wcs[d*97 + c] * cat_s[c*T_ + t];
    xg[(((size_t)b*T_ + t)*N_ + n)*64 + d] = acc;
  }
}

// ---------------- fused qkv projection (144 channels) ----------------
__global__ void qkv_k(const float* __restrict__ xg, const float* __restrict__ Wall,
                      float* __restrict__ qkv){
  int bid = blockIdx.x;
  int nt = bid % 21; int bt = bid / 21;   // bt in [0, 192)
  int n0 = nt * 16;
  __shared__ float Ws[144*65], xs[16*64];
  int tid = threadIdx.x;
  for (int idx = tid; idx < 144*64; idx += 256){ int j = idx >> 6, d = idx & 63; Ws[j*65 + d] = Wall[idx]; }
  for (int idx = tid; idx < 16*64; idx += 256){
    int nn = idx >> 6, d = idx & 63; int n = n0 + nn;
    xs[idx] = (n < N_) ? xg[((size_t)bt*N_ + n)*64 + d] : 0.f;
  }
  __syncthreads();
  for (int idx = tid; idx < 16*144; idx += 256){
    int nn = idx / 144, j = idx % 144;
    int n = n0 + nn; if (n >= N_) continue;
    float acc = 0.f;
    const float* wrow = Ws + j*65; const float* xrow = xs + nn*64;
    for (int d = 0; d < 64; ++d) acc += wrow[d] * xrow[d];
    qkv[((size_t)bt*N_ + n)*144 + j] = acc;
  }
}

// ---------------- temporal attention (2 heads over T) ----------------
__global__ void tattn(const float* __restrict__ qkv, float* __restrict__ att){
  int bid = blockIdx.x; int b = bid / N_, n = bid % N_;
  __shared__ float qs[T_*48], ss[2*T_*T_];
  int tid = threadIdx.x;
  for (int idx = tid; idx < T_*48; idx += 64){
    int t = idx / 48, j = idx % 48;
    qs[idx] = qkv[(((size_t)b*T_ + t)*N_ + n)*144 + j];
  }
  __syncthreads();
  const float scale = 0.35355339059327373f;
  for (int idx = tid; idx < 2*T_*T_; idx += 64){
    int hh = idx / 144, r = (idx / T_) % T_, c = idx % T_;
    float acc = 0.f;
    for (int d = 0; d < 8; ++d) acc += qs[r*48 + hh*8 + d] * qs[c*48 + 16 + hh*8 + d];
    ss[idx] = acc * scale;
  }
  __syncthreads();
  if (tid < 2*T_){
    int hh = tid / T_, r = tid % T_;
    float* row = ss + hh*144 + r*T_;
    float m = -INFINITY; for (int k = 0; k < T_; ++k) m = fmaxf(m, row[k]);
    float s = 0.f; for (int k = 0; k < T_; ++k){ float e = __expf(row[k] - m); row[k] = e; s += e; }
    float inv = 1.f / s; for (int k = 0; k < T_; ++k) row[k] *= inv;
  }
  __syncthreads();
  for (int idx = tid; idx < T_*16; idx += 64){
    int t = idx / 16, o = idx % 16; int hh = o / 8, d = o % 8;
    float acc = 0.f;
    const float* row = ss + hh*144 + t*T_;
    for (int k = 0; k < T_; ++k) acc += row[k] * qs[k*48 + 32 + hh*8 + d];
    att[(((size_t)b*T_ + t)*N_ + n)*48 + o] = acc;
  }
}

// ---------------- geo attention (4 heads over N, masked) ----------------
__global__ void gattn(const float* __restrict__ qkv, const unsigned char* __restrict__ gmask,
                      float* __restrict__ att){
  int bid = blockIdx.x;
  int h = bid & 3; int bt = bid >> 2;     // bt in [0, 192)
  __shared__ float Kt[8*336], Vt[8*336];
  int tid = threadIdx.x;
  for (int idx = tid; idx < N_*8; idx += 256){
    int k = idx >> 3, d = idx & 7;
    const float* row = qkv + ((size_t)bt*N_ + k)*144;
    Kt[d*336 + k] = row[80  + h*8 + d];
    Vt[d*336 + k] = row[112 + h*8 + d];
  }
  __syncthreads();
  int wave = tid >> 6, lane = tid & 63;
  const float scale = 0.35355339059327373f;
  for (int q = wave; q < N_; q += 4){
    const float* qrow = qkv + ((size_t)bt*N_ + q)*144 + 48 + h*8;
    float qv[8];
    #pragma unroll
    for (int d = 0; d < 8; ++d) qv[d] = qrow[d];
    const unsigned char* mrow = gmask + (size_t)q*N_;
    float p[6]; float m = -INFINITY;
    #pragma unroll
    for (int it = 0; it < 6; ++it){
      int k = lane + it*64;
      float s = -INFINITY;
      if (k < N_ && !mrow[k]){
        s = 0.f;
        #pragma unroll
        for (int d = 0; d < 8; ++d) s += qv[d] * Kt[d*336 + k];
        s *= scale;
      }
      p[it] = s; m = fmaxf(m, s);
    }
    #pragma unroll
    for (int off = 32; off; off >>= 1) m = fmaxf(m, __shfl_xor(m, off));
    float sum = 0.f;
    #pragma unroll
    for (int it = 0; it < 6; ++it){
      float e = (p[it] == -INFINITY) ? 0.f : __expf(p[it] - m);
      p[it] = e; sum += e;
    }
    #pragma unroll
    for (int off = 32; off; off >>= 1) sum += __shfl_xor(sum, off);
    float inv = (sum > 0.f) ? 1.f / sum : 0.f;   // guard: never NaN even if mask decode is wrong
    float o8[8] = {0,0,0,0,0,0,0,0};
    #pragma unroll
    for (int it = 0; it < 6; ++it){
      int k = lane + it*64;
      if (k < N_){
        float pp = p[it];
        #pragma unroll
        for (int d = 0; d < 8; ++d) o8[d] += pp * Vt[d*336 + k];
      }
    }
    float* orow = att + ((size_t)bt*N_ + q)*48 + 16 + h*8;
    #pragma unroll
    for (int d = 0; d < 8; ++d){
      float v = o8[d];
      #pragma unroll
      for (int off = 32; off; off >>= 1) v += __shfl_xor(v, off);
      if (lane == d) orow[d] = v * inv;
    }
  }
}

// ---------------- final projection ----------------
__global__ void proj_k(const float* __restrict__ att, const float* __restrict__ W_proj,
                       const float* __restrict__ b_proj, float* __restrict__ out){
  int bid = blockIdx.x;
  long r0 = (long)bid * 16;
  __shared__ float Ws[64*49], as[16*48], bs[64];
  int tid = threadIdx.x;
  for (int idx = tid; idx < 64*48; idx += 256){ int d = idx/48, j = idx%48; Ws[d*49 + j] = W_proj[idx]; }
  if (tid < 64) bs[tid] = b_proj[tid];
  for (int idx = tid; idx < 16*48; idx += 256){
    long r = r0 + idx/48;
    as[idx] = (r < (long)B_*T_*N_) ? att[r*48 + idx%48] : 0.f;
  }
  __syncthreads();
  for (int idx = tid; idx < 16*64; idx += 256){
    int rr = idx >> 6, d = idx & 63;
    long r = r0 + rr;
    if (r >= (long)B_*T_*N_) continue;
    float acc = bs[d];
    const float* w = Ws + d*49; const float* a = as + rr*48;
    for (int j = 0; j < 48; ++j) acc += w[j] * a[j];
    out[r*64 + d] = acc;
  }
}

extern "C" void kernel_launch(void* const* d_in, const int* in_sizes, int n_in,
                              void* d_out, int out_size, void* d_ws, size_t ws_size,
                              hipStream_t stream){
  const float* x      = (const float*)d_in[0];
  const int*   ind    = (const int*)  d_in[1];
  // d_in[2], d_in[3]: x_patterns / pattern_keys (unused by reference math)
  const unsigned char* gmask_raw = (const unsigned char*)d_in[4];
  const float* p1     = (const float*)d_in[5];
  const float* p2     = (const float*)d_in[6];
  const float* p3     = (const float*)d_in[7];
  const float* pk     = (const float*)d_in[8];
  const float* W_r1   = (const float*)d_in[9];
  const float* b_r1   = (const float*)d_in[10];
  const float* W_gcn  = (const float*)d_in[11];
  const float* b_gcn  = (const float*)d_in[12];
  const float* W_r2   = (const float*)d_in[13];
  const float* b_r2   = (const float*)d_in[14];
  const float* Wtq    = (const float*)d_in[15];
  const float* Wtk    = (const float*)d_in[16];
  const float* Wtv    = (const float*)d_in[17];
  const float* Wgq    = (const float*)d_in[18];
  const float* Wgk    = (const float*)d_in[19];
  const float* Wgv    = (const float*)d_in[20];
  const float* W_proj = (const float*)d_in[21];
  const float* b_proj = (const float*)d_in[22];
  float* out = (float*)d_out;

  float* ws = (float*)d_ws;
  float* adp  = ws; ws += (size_t)B_*N_*N_;        // 1,690,000
  float* A1   = ws; ws += B_*DIMS_*DIMS_;          // 25,600
  float* h    = ws; ws += (size_t)B_*N_*384;       // 1,996,800
  float* x1   = ws; ws += (size_t)B_*N_*384;
  float* x2   = ws; ws += (size_t)B_*N_*384;
  float* Wc   = ws; ws += 64*96;
  float* bc   = ws; ws += 64;
  float* Wall = ws; ws += 144*64;
  float* xg   = ws; ws += (size_t)B_*T_*N_*64;     // 3,993,600
  float* qkv  = ws; ws += (size_t)B_*T_*N_*144;    // 8,985,600
  float* att  = ws; ws += (size_t)B_*T_*N_*48;     // 2,995,200
  int*   mmode = (int*)ws; ws += 16;
  unsigned char* msk = (unsigned char*)ws;          // N*N bytes

  mask_detect <<<1,         256, 0, stream>>>(gmask_raw, mmode);
  mask_conv   <<<(N_*N_+255)/256, 256, 0, stream>>>(gmask_raw, mmode, msk);
  dg_a1       <<<B_,        256, 0, stream>>>(p1, pk, ind, A1);
  dg_adp      <<<B_*N_,     128, 0, stream>>>(p2, p3, A1, adp);
  prep_weights<<<2,         256, 0, stream>>>(W_gcn, b_gcn, W_r2, b_r2,
                                              Wtq, Wtk, Wtv, Wgq, Wgk, Wgv, Wc, bc, Wall);
  hproj       <<<B_*N_,     384, 0, stream>>>(x, W_r1, b_r1, h);
  gcn_mm      <<<B_*41,     384, 0, stream>>>(adp, h,  x1);
  gcn_mm      <<<B_*41,     384, 0, stream>>>(adp, x1, x2);
  xg_k        <<<B_*N_,     256, 0, stream>>>(h, x1, x2, Wc, bc, xg);
  qkv_k       <<<192*21,    256, 0, stream>>>(xg, Wall, qkv);
  tattn       <<<B_*N_,      64, 0, stream>>>(qkv, att);
  gattn       <<<768,       256, 0, stream>>>(qkv, msk, att);
  proj_k      <<<3900,      256, 0, stream>>>(att, W_proj, b_proj, out);
}

// Round 3
// 416.843 us; speedup vs baseline: 1.4507x; 1.4507x over previous
//
#include <hip/hip_runtime.h>
#include <hip/hip_bf16.h>
#include <math.h>

#define B_ 16
#define T_ 12
#define N_ 325
#define DIMS_ 40
#define DAYS_ 288
#define MW 12          // bitmask words per mask row (11 used, 1 pad)
#define KPAD 352       // 11*32, padded K/V count in gattn LDS

// ---------------- mask dtype detection + bitmask build ----------------
// geo_mask is bool in the reference; harness may push it as uint8/int32/bf16/f32.
// modes: 0=uint8, 1=int32, 2=bf16, 3=f32
__global__ void mask_detect(const unsigned char* __restrict__ raw, int* __restrict__ mode){
  __shared__ int f3F_m1, f3F_m3, fNZ_o;
  if (threadIdx.x == 0){ f3F_m1 = 0; f3F_m3 = 0; fNZ_o = 0; }
  __syncthreads();
  for (int i = threadIdx.x; i < 4096; i += 256){
    unsigned char v = raw[i];
    int m4 = i & 3;
    if (v == 0x3F && m4 == 1) atomicOr(&f3F_m1, 1);
    if (v == 0x3F && m4 == 3) atomicOr(&f3F_m3, 1);
    if (v != 0 && m4 != 0)    atomicOr(&fNZ_o, 1);
  }
  __syncthreads();
  if (threadIdx.x == 0){
    int m;
    if (f3F_m1) m = 2;
    else if (f3F_m3) m = 3;
    else if (fNZ_o) m = 0;
    else m = 1;
    *mode = m;
  }
}

// bm[q*MW + w] bit j = mask[q][w*32+j] (1 = masked / -inf); out-of-range -> 1
__global__ void mask_bits(const unsigned char* __restrict__ raw, const int* __restrict__ mode_p,
                          unsigned* __restrict__ bm){
  int mode = *mode_p;
  int idx = blockIdx.x * 256 + threadIdx.x;
  if (idx >= N_ * MW) return;
  int q = idx / MW, w = idx % MW;
  unsigned bits = 0;
  for (int j = 0; j < 32; ++j){
    int k = w*32 + j;
    int v;
    if (k >= N_) v = 1;
    else {
      size_t i = (size_t)q*N_ + k;
      if (mode == 0)      v = raw[i] != 0;
      else if (mode == 1) v = ((const int*)raw)[i] != 0;
      else if (mode == 2) { unsigned short u = ((const unsigned short*)raw)[i]; v = (u & 0x7FFF) != 0; }
      else                { float f = ((const float*)raw)[i]; v = (f != 0.f); }
    }
    bits |= (unsigned)v << j;
  }
  bm[idx] = bits;
}

// ---------------- dynamic graph construct ----------------
__global__ void dg_a1(const float* __restrict__ p1, const float* __restrict__ pk,
                      const int* __restrict__ ind, float* __restrict__ A1){
  int b = blockIdx.x;
  __shared__ float te[DIMS_];
  int day = ind[b] % DAYS_; if (day < 0) day += DAYS_;
  for (int i = threadIdx.x; i < DIMS_; i += blockDim.x) te[i] = p1[day*DIMS_ + i];
  __syncthreads();
  for (int jk = threadIdx.x; jk < DIMS_*DIMS_; jk += blockDim.x){
    float acc = 0.f;
    for (int i = 0; i < DIMS_; ++i) acc += te[i] * pk[i*DIMS_*DIMS_ + jk];
    A1[b*DIMS_*DIMS_ + jk] = acc;
  }
}

__global__ void dg_adp(const float* __restrict__ p2, const float* __restrict__ p3,
                       const float* __restrict__ A1, float* __restrict__ adp){
  int bid = blockIdx.x; int b = bid / N_; int n = bid % N_;
  __shared__ float p2r[DIMS_], t2[DIMS_], sbuf[N_], red[128];
  int tid = threadIdx.x;
  if (tid < DIMS_) p2r[tid] = p2[n*DIMS_ + tid];
  __syncthreads();
  if (tid < DIMS_){
    float acc = 0.f;
    const float* a1 = A1 + b*DIMS_*DIMS_;
    for (int j = 0; j < DIMS_; ++j) acc += p2r[j] * a1[j*DIMS_ + tid];
    t2[tid] = acc;
  }
  __syncthreads();
  float lm = -INFINITY;
  for (int c = tid; c < N_; c += 128){
    float acc = 0.f;
    for (int k = 0; k < DIMS_; ++k) acc += p3[c*DIMS_ + k] * t2[k];
    acc = fmaxf(acc, 0.f);
    sbuf[c] = acc; lm = fmaxf(lm, acc);
  }
  red[tid] = lm; __syncthreads();
  for (int off = 64; off; off >>= 1){ if (tid < off) red[tid] = fmaxf(red[tid], red[tid+off]); __syncthreads(); }
  float m = red[0]; __syncthreads();
  float ls = 0.f;
  for (int c = tid; c < N_; c += 128){ float e = __expf(sbuf[c] - m); sbuf[c] = e; ls += e; }
  red[tid] = ls; __syncthreads();
  for (int off = 64; off; off >>= 1){ if (tid < off) red[tid] += red[tid+off]; __syncthreads(); }
  float inv = 1.f / red[0];
  float* outp = adp + ((size_t)b*N_ + n) * N_;
  for (int c = tid; c < N_; c += 128) outp[c] = sbuf[c] * inv;
}

// ---------------- weight prep ----------------
__global__ void prep_weights(const float* W_gcn, const float* b_gcn, const float* W_r2, const float* b_r2,
                             const float* Wtq, const float* Wtk, const float* Wtv,
                             const float* Wgq, const float* Wgk, const float* Wgv,
                             float* Wc, float* bc, float* Wall){
  if (blockIdx.x == 0){
    for (int idx = threadIdx.x; idx < 64*96; idx += blockDim.x){
      int d = idx / 96, c = idx % 96;
      float acc = 0.f;
      for (int o = 0; o < 32; ++o) acc += W_r2[d*32 + o] * W_gcn[o*96 + c];
      Wc[idx] = acc;
    }
    for (int d = threadIdx.x; d < 64; d += blockDim.x){
      float acc = b_r2[d];
      for (int o = 0; o < 32; ++o) acc += W_r2[d*32 + o] * b_gcn[o];
      bc[d] = acc;
    }
  } else {
    for (int idx = threadIdx.x; idx < 144*64; idx += blockDim.x){
      int j = idx >> 6, d = idx & 63;
      const float* src; int r;
      if      (j < 16) { src = Wtq; r = j; }
      else if (j < 32) { src = Wtk; r = j - 16; }
      else if (j < 48) { src = Wtv; r = j - 32; }
      else if (j < 80) { src = Wgq; r = j - 48; }
      else if (j < 112){ src = Wgk; r = j - 80; }
      else             { src = Wgv; r = j - 112; }
      Wall[idx] = src[r*64 + d];
    }
  }
}

// ---------------- h projection ----------------
__global__ void hproj(const float* __restrict__ x, const float* __restrict__ W_r1,
                      const float* __restrict__ b_r1, float* __restrict__ h){
  int bid = blockIdx.x; int b = bid / N_, n = bid % N_;
  __shared__ float xs[T_*65], Ws[32*65];
  int tid = threadIdx.x;
  for (int idx = tid; idx < 32*64; idx += 384){ int c = idx >> 6, d = idx & 63; Ws[c*65 + d] = W_r1[idx]; }
  for (int idx = tid; idx < T_*64; idx += 384){
    int t = idx >> 6, d = idx & 63;
    xs[t*65 + d] = x[(((size_t)b*T_ + t)*N_ + n)*64 + d];
  }
  __syncthreads();
  int c = tid / T_, t = tid % T_;
  float acc = b_r1[c];
  for (int d = 0; d < 64; ++d) acc += xs[t*65 + d] * Ws[c*65 + d];
  h[((size_t)b*N_ + n)*384 + c*T_ + t] = acc;
}

// ---------------- GCN hop ----------------
__global__ void gcn_mm(const float* __restrict__ adp, const float* __restrict__ in,
                       float* __restrict__ out){
  int bid = blockIdx.x;
  int b = bid / 41, wt = bid % 41;
  int w0 = wt * 8;
  __shared__ float a_s[8*64];
  int tid = threadIdx.x;
  float acc[8] = {0,0,0,0,0,0,0,0};
  const float* inb = in + (size_t)b*N_*384 + tid;
  const float* adpb = adp + (size_t)b*N_*N_;
  for (int v0 = 0; v0 < N_; v0 += 64){
    int vn = N_ - v0; if (vn > 64) vn = 64;
    __syncthreads();
    for (int idx = tid; idx < 8*64; idx += 384){
      int wr = idx >> 6, v = idx & 63;
      int w = w0 + wr;
      a_s[idx] = (w < N_ && v < vn) ? adpb[(size_t)w*N_ + v0 + v] : 0.f;
    }
    __syncthreads();
    for (int v = 0; v < vn; ++v){
      float hv = inb[(size_t)(v0 + v)*384];
      #pragma unroll
      for (int w8 = 0; w8 < 8; ++w8) acc[w8] += a_s[w8*64 + v] * hv;
    }
  }
  for (int w8 = 0; w8 < 8; ++w8){
    int w = w0 + w8;
    if (w < N_) out[((size_t)b*N_ + w)*384 + tid] = acc[w8];
  }
}

// ---------------- fused gcn-mlp + reshape2 ----------------
__global__ void xg_k(const float* __restrict__ h, const float* __restrict__ x1,
                     const float* __restrict__ x2, const float* __restrict__ Wc,
                     const float* __restrict__ bc, float* __restrict__ xg){
  int bid = blockIdx.x; int b = bid / N_, n = bid % N_;
  __shared__ float Wcs[64*97], cat_s[96*T_], bcs[64];
  int tid = threadIdx.x;
  for (int idx = tid; idx < 64*96; idx += 256){ int d = idx/96, c = idx%96; Wcs[d*97 + c] = Wc[idx]; }
  if (tid < 64) bcs[tid] = bc[tid];
  size_t base = ((size_t)b*N_ + n)*384;
  for (int idx = tid; idx < 384; idx += 256){
    cat_s[idx]       = h [base + idx];
    cat_s[384 + idx] = x1[base + idx];
    cat_s[768 + idx] = x2[base + idx];
  }
  __syncthreads();
  for (int o = tid; o < 768; o += 256){
    int t = o >> 6, d = o & 63;
    float acc = bcs[d];
    for (int c = 0; c < 96; ++c) acc += Wcs[d*97 + c] * cat_s[c*T_ + t];
    xg[(((size_t)b*T_ + t)*N_ + n)*64 + d] = acc;
  }
}

// ---------------- fused qkv projection ----------------
__global__ void qkv_k(const float* __restrict__ xg, const float* __restrict__ Wall,
                      float* __restrict__ qkv){
  int bid = blockIdx.x;
  int nt = bid % 21; int bt = bid / 21;
  int n0 = nt * 16;
  __shared__ float Ws[144*65], xs[16*64];
  int tid = threadIdx.x;
  for (int idx = tid; idx < 144*64; idx += 256){ int j = idx >> 6, d = idx & 63; Ws[j*65 + d] = Wall[idx]; }
  for (int idx = tid; idx < 16*64; idx += 256){
    int nn = idx >> 6, d = idx & 63; int n = n0 + nn;
    xs[idx] = (n < N_) ? xg[((size_t)bt*N_ + n)*64 + d] : 0.f;
  }
  __syncthreads();
  for (int idx = tid; idx < 16*144; idx += 256){
    int nn = idx / 144, j = idx % 144;
    int n = n0 + nn; if (n >= N_) continue;
    float acc = 0.f;
    const float* wrow = Ws + j*65; const float* xrow = xs + nn*64;
    for (int d = 0; d < 64; ++d) acc += wrow[d] * xrow[d];
    qkv[((size_t)bt*N_ + n)*144 + j] = acc;
  }
}

// ---------------- temporal attention ----------------
__global__ void tattn(const float* __restrict__ qkv, float* __restrict__ att){
  int bid = blockIdx.x; int b = bid / N_, n = bid % N_;
  __shared__ float qs[T_*48], ss[2*T_*T_];
  int tid = threadIdx.x;
  for (int idx = tid; idx < T_*48; idx += 64){
    int t = idx / 48, j = idx % 48;
    qs[idx] = qkv[(((size_t)b*T_ + t)*N_ + n)*144 + j];
  }
  __syncthreads();
  const float scale = 0.35355339059327373f;
  for (int idx = tid; idx < 2*T_*T_; idx += 64){
    int hh = idx / 144, r = (idx / T_) % T_, c = idx % T_;
    float acc = 0.f;
    for (int d = 0; d < 8; ++d) acc += qs[r*48 + hh*8 + d] * qs[c*48 + 16 + hh*8 + d];
    ss[idx] = acc * scale;
  }
  __syncthreads();
  if (tid < 2*T_){
    int hh = tid / T_, r = tid % T_;
    float* row = ss + hh*144 + r*T_;
    float m = -INFINITY; for (int k = 0; k < T_; ++k) m = fmaxf(m, row[k]);
    float s = 0.f; for (int k = 0; k < T_; ++k){ float e = __expf(row[k] - m); row[k] = e; s += e; }
    float inv = 1.f / s; for (int k = 0; k < T_; ++k) row[k] *= inv;
  }
  __syncthreads();
  for (int idx = tid; idx < T_*16; idx += 64){
    int t = idx / 16, o = idx % 16; int hh = o / 8, d = o % 8;
    float acc = 0.f;
    const float* row = ss + hh*144 + t*T_;
    for (int k = 0; k < T_; ++k) acc += row[k] * qs[k*48 + 32 + hh*8 + d];
    att[(((size_t)b*T_ + t)*N_ + n)*48 + o] = acc;
  }
}

// ---------------- geo attention: one query per LANE, bitmask, online softmax ----------------
__global__ __launch_bounds__(384) void gattn(const float* __restrict__ qkv,
                                             const unsigned* __restrict__ bm,
                                             float* __restrict__ att){
  int bid = blockIdx.x;
  int h = bid & 3; int bt = bid >> 2;     // bt in [0, 192)
  __shared__ float Ks[KPAD*8], Vs[KPAD*8];
  int tid = threadIdx.x;
  // stage K,V k-major; zero-pad k in [N_, KPAD)
  for (int idx = tid; idx < KPAD*8; idx += 384){
    int k = idx >> 3, d = idx & 7;
    float kv = 0.f, vv = 0.f;
    if (k < N_){
      const float* row = qkv + ((size_t)bt*N_ + k)*144;
      kv = row[80  + h*8 + d];
      vv = row[112 + h*8 + d];
    }
    Ks[idx] = kv; Vs[idx] = vv;
  }
  __syncthreads();
  int q = tid;
  if (q >= N_) return;
  const float scale = 0.35355339059327373f;
  const float* qrow = qkv + ((size_t)bt*N_ + q)*144 + 48 + h*8;
  float qv[8];
  #pragma unroll
  for (int d = 0; d < 8; ++d) qv[d] = qrow[d] * scale;
  const unsigned* bmr = bm + q*MW;
  const float MASKED = -1e30f;
  float m = -1e28f, sum = 0.f;
  float o8[8] = {0,0,0,0,0,0,0,0};
  for (int w = 0; w < 11; ++w){
    unsigned bits = bmr[w];
    int kbase = w*32;
    #pragma unroll
    for (int g = 0; g < 8; ++g){
      float s4[4]; float gm = MASKED;
      #pragma unroll
      for (int j = 0; j < 4; ++j){
        const float* kr = Ks + (size_t)(kbase + g*4 + j)*8;
        float s = qv[0]*kr[0] + qv[1]*kr[1] + qv[2]*kr[2] + qv[3]*kr[3]
                + qv[4]*kr[4] + qv[5]*kr[5] + qv[6]*kr[6] + qv[7]*kr[7];
        s = ((bits >> (g*4 + j)) & 1u) ? MASKED : s;
        s4[j] = s; gm = fmaxf(gm, s);
      }
      if (gm > m){                        // rare: running max increased
        float r = __expf(m - gm);
        sum *= r;
        #pragma unroll
        for (int d = 0; d < 8; ++d) o8[d] *= r;
        m = gm;
      }
      #pragma unroll
      for (int j = 0; j < 4; ++j){
        float e = __expf(s4[j] - m);      // masked -> exp(-huge) = 0
        sum += e;
        const float* vr = Vs + (size_t)(kbase + g*4 + j)*8;
        #pragma unroll
        for (int d = 0; d < 8; ++d) o8[d] += e * vr[d];
      }
    }
  }
  float inv = (sum > 0.f) ? 1.f / sum : 0.f;
  float* orow = att + ((size_t)bt*N_ + q)*48 + 16 + h*8;
  #pragma unroll
  for (int d = 0; d < 8; ++d) orow[d] = o8[d] * inv;
}

// ---------------- final projection ----------------
__global__ void proj_k(const float* __restrict__ att, const float* __restrict__ W_proj,
                       const float* __restrict__ b_proj, float* __restrict__ out){
  int bid = blockIdx.x;
  long r0 = (long)bid * 16;
  __shared__ float Ws[64*49], as[16*48], bs[64];
  int tid = threadIdx.x;
  for (int idx = tid; idx < 64*48; idx += 256){ int d = idx/48, j = idx%48; Ws[d*49 + j] = W_proj[idx]; }
  if (tid < 64) bs[tid] = b_proj[tid];
  for (int idx = tid; idx < 16*48; idx += 256){
    long r = r0 + idx/48;
    as[idx] = (r < (long)B_*T_*N_) ? att[r*48 + idx%48] : 0.f;
  }
  __syncthreads();
  for (int idx = tid; idx < 16*64; idx += 256){
    int rr = idx >> 6, d = idx & 63;
    long r = r0 + rr;
    if (r >= (long)B_*T_*N_) continue;
    float acc = bs[d];
    const float* w = Ws + d*49; const float* a = as + rr*48;
    for (int j = 0; j < 48; ++j) acc += w[j] * a[j];
    out[r*64 + d] = acc;
  }
}

extern "C" void kernel_launch(void* const* d_in, const int* in_sizes, int n_in,
                              void* d_out, int out_size, void* d_ws, size_t ws_size,
                              hipStream_t stream){
  const float* x      = (const float*)d_in[0];
  const int*   ind    = (const int*)  d_in[1];
  const unsigned char* gmask_raw = (const unsigned char*)d_in[4];
  const float* p1     = (const float*)d_in[5];
  const float* p2     = (const float*)d_in[6];
  const float* p3     = (const float*)d_in[7];
  const float* pk     = (const float*)d_in[8];
  const float* W_r1   = (const float*)d_in[9];
  const float* b_r1   = (const float*)d_in[10];
  const float* W_gcn  = (const float*)d_in[11];
  const float* b_gcn  = (const float*)d_in[12];
  const float* W_r2   = (const float*)d_in[13];
  const float* b_r2   = (const float*)d_in[14];
  const float* Wtq    = (const float*)d_in[15];
  const float* Wtk    = (const float*)d_in[16];
  const float* Wtv    = (const float*)d_in[17];
  const float* Wgq    = (const float*)d_in[18];
  const float* Wgk    = (const float*)d_in[19];
  const float* Wgv    = (const float*)d_in[20];
  const float* W_proj = (const float*)d_in[21];
  const float* b_proj = (const float*)d_in[22];
  float* out = (float*)d_out;

  float* ws = (float*)d_ws;
  float* adp  = ws; ws += (size_t)B_*N_*N_;
  float* A1   = ws; ws += B_*DIMS_*DIMS_;
  float* h    = ws; ws += (size_t)B_*N_*384;
  float* x1   = ws; ws += (size_t)B_*N_*384;
  float* x2   = ws; ws += (size_t)B_*N_*384;
  float* Wc   = ws; ws += 64*96;
  float* bc   = ws; ws += 64;
  float* Wall = ws; ws += 144*64;
  float* xg   = ws; ws += (size_t)B_*T_*N_*64;
  float* qkv  = ws; ws += (size_t)B_*T_*N_*144;
  float* att  = ws; ws += (size_t)B_*T_*N_*48;
  int*   mmode = (int*)ws; ws += 16;
  unsigned* bm = (unsigned*)ws; ws += N_*MW;

  mask_detect <<<1,         256, 0, stream>>>(gmask_raw, mmode);
  mask_bits   <<<(N_*MW+255)/256, 256, 0, stream>>>(gmask_raw, mmode, bm);
  dg_a1       <<<B_,        256, 0, stream>>>(p1, pk, ind, A1);
  dg_adp      <<<B_*N_,     128, 0, stream>>>(p2, p3, A1, adp);
  prep_weights<<<2,         256, 0, stream>>>(W_gcn, b_gcn, W_r2, b_r2,
                                              Wtq, Wtk, Wtv, Wgq, Wgk, Wgv, Wc, bc, Wall);
  hproj       <<<B_*N_,     384, 0, stream>>>(x, W_r1, b_r1, h);
  gcn_mm      <<<B_*41,     384, 0, stream>>>(adp, h,  x1);
  gcn_mm      <<<B_*41,     384, 0, stream>>>(adp, x1, x2);
  xg_k        <<<B_*N_,     256, 0, stream>>>(h, x1, x2, Wc, bc, xg);
  qkv_k       <<<192*21,    256, 0, stream>>>(xg, Wall, qkv);
  tattn       <<<B_*N_,      64, 0, stream>>>(qkv, att);
  gattn       <<<768,       384, 0, stream>>>(qkv, bm, att);
  proj_k      <<<3900,      256, 0, stream>>>(att, W_proj, b_proj, out);
}